// Round 3
// baseline (1696.922 us; speedup 1.0000x reference)
//
#include <hip/hip_runtime.h>

#define THREADS 256
#define PART_T 8192      // edges per partition tile
#define NF_PAD 1024      // padded bucket count (NF = ceil(N/64) <= 1024)

// ---------------------------------------------------------------------------
// Detect whether the raw index array is int64 (high words all zero) or int32.
// ---------------------------------------------------------------------------
__global__ void detect_i64(const unsigned* __restrict__ raw, int* __restrict__ flag) {
    __shared__ int nz;
    if (threadIdx.x == 0) nz = 0;
    __syncthreads();
    int found = 0;
    for (int i = threadIdx.x; i < 2048; i += blockDim.x) {
        if (raw[2 * i + 1] != 0u) found = 1;
    }
    if (found) atomicOr(&nz, 1);
    __syncthreads();
    if (threadIdx.x == 0) *flag = nz ? 0 : 1;  // 1 => int64
}

// Count in-degree straight from the raw dst half.
__global__ void deg_count(const int* __restrict__ raw, int E, int* __restrict__ deg,
                          const int* __restrict__ flag) {
    int i = blockIdx.x * blockDim.x + threadIdx.x;
    if (i < E) {
        int d = (*flag) ? raw[2 * (E + i)] : raw[E + i];
        atomicAdd(&deg[d], 1);
    }
}

__global__ void convert_idx(const int* __restrict__ raw, int* __restrict__ out,
                            int n, const int* __restrict__ flag) {
    int i = blockIdx.x * blockDim.x + threadIdx.x;
    if (i < n) out[i] = (*flag) ? raw[2 * i] : raw[i];
}

__global__ void compute_dis(const int* __restrict__ deg, float* __restrict__ dis, int n) {
    int i = blockIdx.x * blockDim.x + threadIdx.x;
    if (i < n) dis[i] = rsqrtf((float)(deg[i] + 1));  // +1 self-loop
}

// ---------------------------------------------------------------------------
// Bucket histogram (64 nodes/bucket) from deg + exclusive scan -> boff, gcur.
// Single block of 1024 threads.
// ---------------------------------------------------------------------------
__global__ __launch_bounds__(1024) void finehist_scan(const int* __restrict__ deg, int n,
                                                      int NF, int E,
                                                      int* __restrict__ boff,
                                                      int* __restrict__ gcur) {
    __shared__ int h[NF_PAD];
    int t = threadIdx.x;
    h[t] = 0;
    __syncthreads();
    for (int i = t; i < n; i += 1024) atomicAdd(&h[i >> 6], deg[i]);
    __syncthreads();
    int v = h[t];
    int inc = v;
    for (int o = 1; o < 1024; o <<= 1) {
        int x = (t >= o) ? h[t - o] : 0;
        __syncthreads();
        h[t] += x;
        __syncthreads();
    }
    inc = h[t];
    int exc = inc - v;
    if (t <= NF) boff[t] = (t == NF) ? E : exc;
    if (t < NF) gcur[t] = exc;
}

// ---------------------------------------------------------------------------
// Partition edges into NF buckets by dst>>6, LDS-staged dense flushes.
// Payload: src | dst<<16 (requires N < 65536). One tile of PART_T per block.
// ---------------------------------------------------------------------------
__global__ __launch_bounds__(256) void partition_edges(const int* __restrict__ raw, int E,
                                                       int NF, int* __restrict__ gcur,
                                                       unsigned* __restrict__ elist,
                                                       const int* __restrict__ flag) {
    __shared__ int cnt[NF_PAD];
    __shared__ int pfx[NF_PAD];
    __shared__ int gbase[NF_PAD];
    __shared__ int tsum[256];
    __shared__ unsigned stage[PART_T];
    int t = threadIdx.x;
    long long base = (long long)blockIdx.x * PART_T;
    int tileN = (int)min((long long)PART_T, (long long)E - base);
    bool f64 = (*flag) != 0;

    for (int i = t; i < NF_PAD; i += 256) cnt[i] = 0;
    __syncthreads();

    // load + histogram (kept in registers)
    unsigned pk[PART_T / 256];
#pragma unroll
    for (int k = 0; k < PART_T / 256; k++) {
        long long e = base + k * 256 + t;
        if (e < (long long)E) {
            int s = f64 ? raw[2 * e] : raw[e];
            int d = f64 ? raw[2 * ((long long)E + e)] : raw[E + e];
            unsigned p = (unsigned)s | ((unsigned)d << 16);
            pk[k] = p;
            atomicAdd(&cnt[d >> 6], 1);
        } else {
            pk[k] = 0xFFFFFFFFu;
        }
    }
    __syncthreads();

    // block exclusive scan of cnt[0..NF_PAD) -> pfx
    int a0 = cnt[4 * t], a1 = cnt[4 * t + 1], a2 = cnt[4 * t + 2], a3 = cnt[4 * t + 3];
    int tot = a0 + a1 + a2 + a3;
    tsum[t] = tot;
    __syncthreads();
    for (int o = 1; o < 256; o <<= 1) {
        int x = (t >= o) ? tsum[t - o] : 0;
        __syncthreads();
        tsum[t] += x;
        __syncthreads();
    }
    int pre = tsum[t] - tot;
    pfx[4 * t] = pre;
    pfx[4 * t + 1] = pre + a0;
    pfx[4 * t + 2] = pre + a0 + a1;
    pfx[4 * t + 3] = pre + a0 + a1 + a2;

    // global cursor reservation, then reset cnt for rank assignment
    for (int i = t; i < NF; i += 256) {
        gbase[i] = (cnt[i] > 0) ? atomicAdd(&gcur[i], cnt[i]) : 0;
    }
    __syncthreads();
    for (int i = t; i < NF_PAD; i += 256) cnt[i] = 0;
    __syncthreads();

    // stage into tile-sorted order
#pragma unroll
    for (int k = 0; k < PART_T / 256; k++) {
        long long e = base + k * 256 + t;
        if (e < (long long)E) {
            unsigned p = pk[k];
            int f = p >> 22;
            int r = atomicAdd(&cnt[f], 1);
            stage[pfx[f] + r] = p;
        }
    }
    __syncthreads();

    // dense flush
    for (int i = t; i < tileN; i += 256) {
        unsigned v = stage[i];
        int f = v >> 22;
        elist[gbase[f] + (i - pfx[f])] = v;
    }
}

// ---------------------------------------------------------------------------
// out[n][64] = dis[n] * (in[n][64] @ W[64][64]).  W kept in 64 VGPRs/thread,
// input staged 4 nodes at a time; 64 nodes per block.
// ---------------------------------------------------------------------------
__global__ __launch_bounds__(256) void linear64(const float* __restrict__ in,
                                                const float* __restrict__ W,
                                                const float* __restrict__ dis,
                                                float* __restrict__ out, int n) {
    __shared__ float sIn[4][64];
    int t = threadIdx.x;
    int ln = t >> 6, od = t & 63;
    float w[64];
#pragma unroll
    for (int k = 0; k < 64; k++) w[k] = W[k * 64 + od];
    int base = blockIdx.x * 64;
    for (int pass = 0; pass < 16; pass++) {
        int node0 = base + pass * 4;
        __syncthreads();
        {
            int nd = node0 + ln;
            sIn[ln][od] = (nd < n) ? in[(long long)nd * 64 + od] : 0.f;
        }
        __syncthreads();
        int node = node0 + ln;
        if (node < n) {
            float acc = 0.f;
#pragma unroll
            for (int k = 0; k < 64; k++) acc += sIn[ln][k] * w[k];
            out[(long long)node * 64 + od] = acc * dis[node];
        }
    }
}

// ---------------------------------------------------------------------------
// Push aggregation: one block per 64-node bucket, LDS accumulator 16KB.
// Wave per edge, lane = feature dim, ds_add_f32 into acc.
// out[d] = relu( dis[d]*(acc[d] + hs[d]) + bias )
// ---------------------------------------------------------------------------
__global__ __launch_bounds__(256) void push_agg(const float* __restrict__ hs,
                                                const unsigned* __restrict__ elist,
                                                const int* __restrict__ boff,
                                                const float* __restrict__ dis,
                                                const float* __restrict__ bias,
                                                float* __restrict__ out, int n) {
    __shared__ float acc[64 * 64];
    int t = threadIdx.x, lane = t & 63, w = t >> 6;
    for (int i = t; i < 4096; i += 256) acc[i] = 0.f;
    __syncthreads();
    int b = blockIdx.x;
    int beg = boff[b], end = boff[b + 1];
    for (int e = beg + w; e < end; e += 4) {
        unsigned v = elist[e];
        int s = v & 0xFFFF;
        int local = (v >> 16) & 63;
        float x = hs[(long long)s * 64 + lane];
        __hip_atomic_fetch_add(&acc[local * 64 + lane], x,
                               __ATOMIC_RELAXED, __HIP_MEMORY_SCOPE_WORKGROUP);
    }
    __syncthreads();
    for (int k = t; k < 4096; k += 256) {
        int local = k >> 6, d2 = k & 63;
        int node = b * 64 + local;
        if (node < n) {
            float val = dis[node] * (acc[k] + hs[(long long)node * 64 + d2]) + bias[d2];
            out[(long long)node * 64 + d2] = val > 0.f ? val : 0.f;
        }
    }
}

// ---------------------------------------------------------------------------
// Mean-pool sum: batch sorted -> per-wave register accumulation.
// ---------------------------------------------------------------------------
__global__ __launch_bounds__(256) void pool_sum(const float* __restrict__ h,
                                                const int* __restrict__ batch,
                                                float* __restrict__ psum,
                                                int* __restrict__ pcnt, int n) {
    int t = threadIdx.x;
    int lane = t & 63;
    int base = (blockIdx.x * 4 + (t >> 6)) * 32;
    float acc = 0.f;
    int g = -1, cnt = 0;
    for (int i = 0; i < 32; i++) {
        int node = base + i;
        if (node >= n) break;
        int bg = batch[node];
        if (bg != g) {
            if (g >= 0) {
                atomicAdd(&psum[g * 64 + lane], acc);
                if (lane == 0) atomicAdd(&pcnt[g], cnt);
            }
            g = bg; acc = 0.f; cnt = 0;
        }
        acc += h[(long long)node * 64 + lane];
        cnt++;
    }
    if (g >= 0) {
        atomicAdd(&psum[g * 64 + lane], acc);
        if (lane == 0) atomicAdd(&pcnt[g], cnt);
    }
}

__global__ __launch_bounds__(640) void final_fc(const float* __restrict__ psum,
                                                const int* __restrict__ pcnt,
                                                const float* __restrict__ Wfc,
                                                const float* __restrict__ bfc,
                                                float* __restrict__ out) {
    __shared__ float sP[64 * 64];
    __shared__ float sW[64 * 10];
    int t = threadIdx.x;
    for (int i = t; i < 4096; i += 640) sP[i] = psum[i];
    if (t < 640) sW[t] = Wfc[t];
    __syncthreads();
    int g = t / 10, c = t % 10;
    float acc = 0.f;
#pragma unroll
    for (int k = 0; k < 64; k++) acc += sP[g * 64 + k] * sW[k * 10 + c];
    float cnt = (float)pcnt[g];
    if (cnt < 1.f) cnt = 1.f;
    out[g * 10 + c] = acc / cnt + bfc[c];
}

static inline int cdiv(long long a, int b) { return (int)((a + b - 1) / b); }

extern "C" void kernel_launch(void* const* d_in, const int* in_sizes, int n_in,
                              void* d_out, int out_size, void* d_ws, size_t ws_size,
                              hipStream_t stream) {
    const float* x    = (const float*)d_in[0];
    const int*   eraw = (const int*)d_in[1];
    const int*   braw = (const int*)d_in[2];
    const float* W1   = (const float*)d_in[3];
    const float* b1   = (const float*)d_in[4];
    const float* W2   = (const float*)d_in[5];
    const float* b2   = (const float*)d_in[6];
    const float* Wfc  = (const float*)d_in[7];
    const float* bfc  = (const float*)d_in[8];
    float* out = (float*)d_out;

    const int N  = in_sizes[0] / 64;   // 50000
    const int E  = in_sizes[1] / 2;    // 1600000
    const int NF = cdiv(N, 64);        // 782 buckets (requires <= NF_PAD)

    // ---- workspace carve (256B-aligned chunks) ----
    char* p = (char*)d_ws;
    auto carve = [&](size_t bytes) { char* q = p; p += (bytes + 255) / 256 * 256; return q; };
    int*      flag   = (int*)carve(4);
    unsigned* elist  = (unsigned*)carve((size_t)E * sizeof(unsigned));
    int*      batchi = (int*)carve((size_t)N * sizeof(int));
    int*      deg    = (int*)carve((size_t)N * sizeof(int));
    int*      boff   = (int*)carve((size_t)(NF + 1) * sizeof(int));
    int*      gcur   = (int*)carve((size_t)NF * sizeof(int));
    float*    dis    = (float*)carve((size_t)N * sizeof(float));
    float*    bufA   = (float*)carve((size_t)N * 64 * sizeof(float));
    float*    bufB   = (float*)carve((size_t)N * 64 * sizeof(float));
    float*    psum   = (float*)carve(64 * 64 * sizeof(float));
    int*      pcnt   = (int*)carve(64 * sizeof(int));

    hipMemsetAsync(deg, 0, (size_t)N * sizeof(int), stream);
    hipMemsetAsync(psum, 0, 64 * 64 * sizeof(float), stream);
    hipMemsetAsync(pcnt, 0, 64 * sizeof(int), stream);

    // ---- index dtype detect, degree, batch convert ----
    detect_i64<<<1, THREADS, 0, stream>>>((const unsigned*)eraw, flag);
    deg_count<<<cdiv(E, THREADS), THREADS, 0, stream>>>(eraw, E, deg, flag);
    convert_idx<<<cdiv(N, THREADS), THREADS, 0, stream>>>(braw, batchi, N, flag);
    compute_dis<<<cdiv(N, THREADS), THREADS, 0, stream>>>(deg, dis, N);

    // ---- bucket offsets + edge partition ----
    finehist_scan<<<1, 1024, 0, stream>>>(deg, N, NF, E, boff, gcur);
    partition_edges<<<cdiv(E, PART_T), 256, 0, stream>>>(eraw, E, NF, gcur, elist, flag);

    // ---- layer 1 ----
    linear64<<<cdiv(N, 64), 256, 0, stream>>>(x, W1, dis, bufA, N);
    push_agg<<<NF, 256, 0, stream>>>(bufA, elist, boff, dis, b1, bufB, N);

    // ---- layer 2 ----
    linear64<<<cdiv(N, 64), 256, 0, stream>>>(bufB, W2, dis, bufA, N);
    push_agg<<<NF, 256, 0, stream>>>(bufA, elist, boff, dis, b2, bufB, N);

    // ---- pool + head ----
    pool_sum<<<cdiv(N, 128), 256, 0, stream>>>(bufB, batchi, psum, pcnt, N);
    final_fc<<<1, 640, 0, stream>>>(psum, pcnt, Wfc, bfc, out);
}

// Round 4
// 409.015 us; speedup vs baseline: 4.1488x; 4.1488x over previous
//
#include <hip/hip_runtime.h>

#define THREADS 256
#define PART_T 8192      // edges per partition tile
#define NF_PAD 1024      // padded bucket count (NF = ceil(N/64) <= 1024)

// ---------------------------------------------------------------------------
// Detect whether the raw index array is int64 (high words all zero) or int32.
// ---------------------------------------------------------------------------
__global__ void detect_i64(const unsigned* __restrict__ raw, int* __restrict__ flag) {
    __shared__ int nz;
    if (threadIdx.x == 0) nz = 0;
    __syncthreads();
    int found = 0;
    for (int i = threadIdx.x; i < 2048; i += blockDim.x) {
        if (raw[2 * i + 1] != 0u) found = 1;
    }
    if (found) atomicOr(&nz, 1);
    __syncthreads();
    if (threadIdx.x == 0) *flag = nz ? 0 : 1;  // 1 => int64
}

// Count in-degree straight from the raw dst half.
__global__ void deg_count(const int* __restrict__ raw, int E, int* __restrict__ deg,
                          const int* __restrict__ flag) {
    int i = blockIdx.x * blockDim.x + threadIdx.x;
    if (i < E) {
        int d = (*flag) ? raw[2 * (E + i)] : raw[E + i];
        atomicAdd(&deg[d], 1);
    }
}

__global__ void convert_idx(const int* __restrict__ raw, int* __restrict__ out,
                            int n, const int* __restrict__ flag) {
    int i = blockIdx.x * blockDim.x + threadIdx.x;
    if (i < n) out[i] = (*flag) ? raw[2 * i] : raw[i];
}

__global__ void compute_dis(const int* __restrict__ deg, float* __restrict__ dis, int n) {
    int i = blockIdx.x * blockDim.x + threadIdx.x;
    if (i < n) dis[i] = rsqrtf((float)(deg[i] + 1));  // +1 self-loop
}

// ---------------------------------------------------------------------------
// Bucket histogram (64 nodes/bucket) from deg + exclusive scan -> boff, gcur.
// Also seeds noff[n] = E.
// ---------------------------------------------------------------------------
__global__ __launch_bounds__(1024) void finehist_scan(const int* __restrict__ deg, int n,
                                                      int NF, int E,
                                                      int* __restrict__ boff,
                                                      int* __restrict__ gcur,
                                                      int* __restrict__ noff) {
    __shared__ int h[NF_PAD];
    int t = threadIdx.x;
    h[t] = 0;
    __syncthreads();
    for (int i = t; i < n; i += 1024) atomicAdd(&h[i >> 6], deg[i]);
    __syncthreads();
    int v = h[t];
    for (int o = 1; o < 1024; o <<= 1) {
        int x = (t >= o) ? h[t - o] : 0;
        __syncthreads();
        h[t] += x;
        __syncthreads();
    }
    int exc = h[t] - v;
    if (t <= NF) boff[t] = (t == NF) ? E : exc;
    if (t < NF) gcur[t] = exc;
    if (t == 0) noff[n] = E;
}

// ---------------------------------------------------------------------------
// Partition edges into NF buckets by dst>>6, LDS-staged dense flushes.
// Payload: src | dst<<16 (requires N < 65536).
// ---------------------------------------------------------------------------
__global__ __launch_bounds__(256) void partition_edges(const int* __restrict__ raw, int E,
                                                       int NF, int* __restrict__ gcur,
                                                       unsigned* __restrict__ elist,
                                                       const int* __restrict__ flag) {
    __shared__ int cnt[NF_PAD];
    __shared__ int pfx[NF_PAD];
    __shared__ int gbase[NF_PAD];
    __shared__ int tsum[256];
    __shared__ unsigned stage[PART_T];
    int t = threadIdx.x;
    long long base = (long long)blockIdx.x * PART_T;
    int tileN = (int)min((long long)PART_T, (long long)E - base);
    bool f64 = (*flag) != 0;

    for (int i = t; i < NF_PAD; i += 256) cnt[i] = 0;
    __syncthreads();

    unsigned pk[PART_T / 256];
#pragma unroll
    for (int k = 0; k < PART_T / 256; k++) {
        long long e = base + k * 256 + t;
        if (e < (long long)E) {
            int s = f64 ? raw[2 * e] : raw[e];
            int d = f64 ? raw[2 * ((long long)E + e)] : raw[E + e];
            unsigned p = (unsigned)s | ((unsigned)d << 16);
            pk[k] = p;
            atomicAdd(&cnt[d >> 6], 1);
        } else {
            pk[k] = 0xFFFFFFFFu;
        }
    }
    __syncthreads();

    // block exclusive scan of cnt -> pfx
    int a0 = cnt[4 * t], a1 = cnt[4 * t + 1], a2 = cnt[4 * t + 2], a3 = cnt[4 * t + 3];
    int tot = a0 + a1 + a2 + a3;
    tsum[t] = tot;
    __syncthreads();
    for (int o = 1; o < 256; o <<= 1) {
        int x = (t >= o) ? tsum[t - o] : 0;
        __syncthreads();
        tsum[t] += x;
        __syncthreads();
    }
    int pre = tsum[t] - tot;
    pfx[4 * t] = pre;
    pfx[4 * t + 1] = pre + a0;
    pfx[4 * t + 2] = pre + a0 + a1;
    pfx[4 * t + 3] = pre + a0 + a1 + a2;

    for (int i = t; i < NF; i += 256) {
        gbase[i] = (cnt[i] > 0) ? atomicAdd(&gcur[i], cnt[i]) : 0;
    }
    __syncthreads();
    for (int i = t; i < NF_PAD; i += 256) cnt[i] = 0;
    __syncthreads();

#pragma unroll
    for (int k = 0; k < PART_T / 256; k++) {
        long long e = base + k * 256 + t;
        if (e < (long long)E) {
            unsigned p = pk[k];
            int f = p >> 22;
            int r = atomicAdd(&cnt[f], 1);
            stage[pfx[f] + r] = p;
        }
    }
    __syncthreads();

    for (int i = t; i < tileN; i += 256) {
        unsigned v = stage[i];
        int f = v >> 22;
        elist[gbase[f] + (i - pfx[f])] = v;
    }
}

// ---------------------------------------------------------------------------
// Exact CSR within each bucket: one block per bucket. LDS ticket cursors
// seeded by an in-wave prefix of deg; single-pass scatter of ushort src.
// Each block owns its [boff[b], boff[b+1]) window -> writes stay in one
// XCD's L2 and write back dense (no line amplification).
// ---------------------------------------------------------------------------
__global__ __launch_bounds__(256) void bucket_csr(const unsigned* __restrict__ elist,
                                                  const int* __restrict__ boff,
                                                  const int* __restrict__ deg,
                                                  int n,
                                                  unsigned short* __restrict__ ssrc,
                                                  int* __restrict__ noff) {
    __shared__ int cur[64];
    int b = blockIdx.x;
    int t = threadIdx.x;
    int beg = boff[b], end = boff[b + 1];
    if (t < 64) {
        int node = b * 64 + t;
        int d = (node < n) ? deg[node] : 0;
        int v = d;
#pragma unroll
        for (int o = 1; o < 64; o <<= 1) {
            int x = __shfl_up(v, o, 64);
            if (t >= o) v += x;
        }
        int exc = beg + v - d;  // exclusive prefix
        cur[t] = exc;
        if (node <= n) noff[node] = exc;  // node==n writes E (consistent)
    }
    __syncthreads();
    for (int e = beg + t; e < end; e += 256) {
        unsigned v = elist[e];
        int local = (v >> 16) & 63;
        int pos = atomicAdd(&cur[local], 1);
        ssrc[pos] = (unsigned short)(v & 0xFFFFu);
    }
}

// ---------------------------------------------------------------------------
// out[n][64] = dis[n] * (in[n][64] @ W[64][64]).  W in 64 VGPRs/thread.
// ---------------------------------------------------------------------------
__global__ __launch_bounds__(256) void linear64(const float* __restrict__ in,
                                                const float* __restrict__ W,
                                                const float* __restrict__ dis,
                                                float* __restrict__ out, int n) {
    __shared__ float sIn[4][64];
    int t = threadIdx.x;
    int ln = t >> 6, od = t & 63;
    float w[64];
#pragma unroll
    for (int k = 0; k < 64; k++) w[k] = W[k * 64 + od];
    int base = blockIdx.x * 64;
    for (int pass = 0; pass < 16; pass++) {
        int node0 = base + pass * 4;
        __syncthreads();
        {
            int nd = node0 + ln;
            sIn[ln][od] = (nd < n) ? in[(long long)nd * 64 + od] : 0.f;
        }
        __syncthreads();
        int node = node0 + ln;
        if (node < n) {
            float acc = 0.f;
#pragma unroll
            for (int k = 0; k < 64; k++) acc += sIn[ln][k] * w[k];
            out[(long long)node * 64 + od] = acc * dis[node];
        }
    }
}

// ---------------------------------------------------------------------------
// Pull aggregation: wave per dst node, lane = dim, 8-deep unroll.
// out[d] = relu( dis[d]*(sum_{s in N(d)} hs[s] + hs[d]) + bias )
// ---------------------------------------------------------------------------
__global__ __launch_bounds__(256) void gather_agg(const float* __restrict__ hs,
                                                  const int* __restrict__ noff,
                                                  const unsigned short* __restrict__ ssrc,
                                                  const float* __restrict__ dis,
                                                  const float* __restrict__ bias,
                                                  float* __restrict__ out, int n) {
    int t = threadIdx.x;
    int lane = t & 63;
    int node = blockIdx.x * 4 + (t >> 6);
    if (node >= n) return;
    int beg = noff[node], end = noff[node + 1];
    float acc = 0.f;
    int e = beg;
    for (; e + 8 <= end; e += 8) {
        int s0 = ssrc[e], s1 = ssrc[e + 1], s2 = ssrc[e + 2], s3 = ssrc[e + 3];
        int s4 = ssrc[e + 4], s5 = ssrc[e + 5], s6 = ssrc[e + 6], s7 = ssrc[e + 7];
        float v0 = hs[(long long)s0 * 64 + lane];
        float v1 = hs[(long long)s1 * 64 + lane];
        float v2 = hs[(long long)s2 * 64 + lane];
        float v3 = hs[(long long)s3 * 64 + lane];
        float v4 = hs[(long long)s4 * 64 + lane];
        float v5 = hs[(long long)s5 * 64 + lane];
        float v6 = hs[(long long)s6 * 64 + lane];
        float v7 = hs[(long long)s7 * 64 + lane];
        acc += ((v0 + v1) + (v2 + v3)) + ((v4 + v5) + (v6 + v7));
    }
    for (; e < end; e++) {
        acc += hs[(long long)ssrc[e] * 64 + lane];
    }
    acc += hs[(long long)node * 64 + lane];  // self-loop
    float v = dis[node] * acc + bias[lane];
    out[(long long)node * 64 + lane] = v > 0.f ? v : 0.f;
}

// ---------------------------------------------------------------------------
// Mean-pool sum: batch sorted -> per-wave register accumulation.
// ---------------------------------------------------------------------------
__global__ __launch_bounds__(256) void pool_sum(const float* __restrict__ h,
                                                const int* __restrict__ batch,
                                                float* __restrict__ psum,
                                                int* __restrict__ pcnt, int n) {
    int t = threadIdx.x;
    int lane = t & 63;
    int base = (blockIdx.x * 4 + (t >> 6)) * 32;
    float acc = 0.f;
    int g = -1, cnt = 0;
    for (int i = 0; i < 32; i++) {
        int node = base + i;
        if (node >= n) break;
        int bg = batch[node];
        if (bg != g) {
            if (g >= 0) {
                atomicAdd(&psum[g * 64 + lane], acc);
                if (lane == 0) atomicAdd(&pcnt[g], cnt);
            }
            g = bg; acc = 0.f; cnt = 0;
        }
        acc += h[(long long)node * 64 + lane];
        cnt++;
    }
    if (g >= 0) {
        atomicAdd(&psum[g * 64 + lane], acc);
        if (lane == 0) atomicAdd(&pcnt[g], cnt);
    }
}

__global__ __launch_bounds__(640) void final_fc(const float* __restrict__ psum,
                                                const int* __restrict__ pcnt,
                                                const float* __restrict__ Wfc,
                                                const float* __restrict__ bfc,
                                                float* __restrict__ out) {
    __shared__ float sP[64 * 64];
    __shared__ float sW[64 * 10];
    int t = threadIdx.x;
    for (int i = t; i < 4096; i += 640) sP[i] = psum[i];
    if (t < 640) sW[t] = Wfc[t];
    __syncthreads();
    int g = t / 10, c = t % 10;
    float acc = 0.f;
#pragma unroll
    for (int k = 0; k < 64; k++) acc += sP[g * 64 + k] * sW[k * 10 + c];
    float cnt = (float)pcnt[g];
    if (cnt < 1.f) cnt = 1.f;
    out[g * 10 + c] = acc / cnt + bfc[c];
}

static inline int cdiv(long long a, int b) { return (int)((a + b - 1) / b); }

extern "C" void kernel_launch(void* const* d_in, const int* in_sizes, int n_in,
                              void* d_out, int out_size, void* d_ws, size_t ws_size,
                              hipStream_t stream) {
    const float* x    = (const float*)d_in[0];
    const int*   eraw = (const int*)d_in[1];
    const int*   braw = (const int*)d_in[2];
    const float* W1   = (const float*)d_in[3];
    const float* b1   = (const float*)d_in[4];
    const float* W2   = (const float*)d_in[5];
    const float* b2   = (const float*)d_in[6];
    const float* Wfc  = (const float*)d_in[7];
    const float* bfc  = (const float*)d_in[8];
    float* out = (float*)d_out;

    const int N  = in_sizes[0] / 64;   // 50000
    const int E  = in_sizes[1] / 2;    // 1600000
    const int NF = cdiv(N, 64);        // 782 buckets

    // ---- workspace carve (256B-aligned chunks) ----
    char* p = (char*)d_ws;
    auto carve = [&](size_t bytes) { char* q = p; p += (bytes + 255) / 256 * 256; return q; };
    int*            flag   = (int*)carve(4);
    unsigned*       elist  = (unsigned*)carve((size_t)E * sizeof(unsigned));
    unsigned short* ssrc   = (unsigned short*)carve((size_t)E * sizeof(unsigned short));
    int*            batchi = (int*)carve((size_t)N * sizeof(int));
    int*            deg    = (int*)carve((size_t)N * sizeof(int));
    int*            boff   = (int*)carve((size_t)(NF + 1) * sizeof(int));
    int*            gcur   = (int*)carve((size_t)NF * sizeof(int));
    int*            noff   = (int*)carve((size_t)(NF * 64 + 1) * sizeof(int));
    float*          dis    = (float*)carve((size_t)N * sizeof(float));
    float*          bufA   = (float*)carve((size_t)N * 64 * sizeof(float));
    float*          bufB   = (float*)carve((size_t)N * 64 * sizeof(float));
    float*          psum   = (float*)carve(64 * 64 * sizeof(float));
    int*            pcnt   = (int*)carve(64 * sizeof(int));

    hipMemsetAsync(deg, 0, (size_t)N * sizeof(int), stream);
    hipMemsetAsync(psum, 0, 64 * 64 * sizeof(float), stream);
    hipMemsetAsync(pcnt, 0, 64 * sizeof(int), stream);

    // ---- index dtype detect, degree, batch convert ----
    detect_i64<<<1, THREADS, 0, stream>>>((const unsigned*)eraw, flag);
    deg_count<<<cdiv(E, THREADS), THREADS, 0, stream>>>(eraw, E, deg, flag);
    convert_idx<<<cdiv(N, THREADS), THREADS, 0, stream>>>(braw, batchi, N, flag);
    compute_dis<<<cdiv(N, THREADS), THREADS, 0, stream>>>(deg, dis, N);

    // ---- bucket offsets + dense partition + exact CSR ----
    finehist_scan<<<1, 1024, 0, stream>>>(deg, N, NF, E, boff, gcur, noff);
    partition_edges<<<cdiv(E, PART_T), 256, 0, stream>>>(eraw, E, NF, gcur, elist, flag);
    bucket_csr<<<NF, 256, 0, stream>>>(elist, boff, deg, N, ssrc, noff);

    // ---- layer 1 ----
    linear64<<<cdiv(N, 64), 256, 0, stream>>>(x, W1, dis, bufA, N);
    gather_agg<<<cdiv(N, 4), 256, 0, stream>>>(bufA, noff, ssrc, dis, b1, bufB, N);

    // ---- layer 2 ----
    linear64<<<cdiv(N, 64), 256, 0, stream>>>(bufB, W2, dis, bufA, N);
    gather_agg<<<cdiv(N, 4), 256, 0, stream>>>(bufA, noff, ssrc, dis, b2, bufB, N);

    // ---- pool + head ----
    pool_sum<<<cdiv(N, 128), 256, 0, stream>>>(bufB, batchi, psum, pcnt, N);
    final_fc<<<1, 640, 0, stream>>>(psum, pcnt, Wfc, bfc, out);
}

// Round 5
// 315.386 us; speedup vs baseline: 5.3805x; 1.2969x over previous
//
#include <hip/hip_runtime.h>

#define THREADS 256
#define PART_T 8192      // edges per partition tile
#define NF_PAD 1024      // padded bucket count (NF = ceil(N/64) <= 1024)

// ---------------------------------------------------------------------------
// Detect whether the raw index array is int64 (high words all zero) or int32.
// ---------------------------------------------------------------------------
__global__ void detect_i64(const unsigned* __restrict__ raw, int* __restrict__ flag) {
    __shared__ int nz;
    if (threadIdx.x == 0) nz = 0;
    __syncthreads();
    int found = 0;
    for (int i = threadIdx.x; i < 2048; i += blockDim.x) {
        if (raw[2 * i + 1] != 0u) found = 1;
    }
    if (found) atomicOr(&nz, 1);
    __syncthreads();
    if (threadIdx.x == 0) *flag = nz ? 0 : 1;  // 1 => int64
}

__global__ void convert_idx(const int* __restrict__ raw, int* __restrict__ out,
                            int n, const int* __restrict__ flag) {
    int i = blockIdx.x * blockDim.x + threadIdx.x;
    if (i < n) out[i] = (*flag) ? raw[2 * i] : raw[i];
}

// ---------------------------------------------------------------------------
// Bucket-level histogram of dst>>6: LDS bins per block, one global flush.
// Replaces the 1.6M-global-atomic deg_count (70 us -> ~10 us).
// ---------------------------------------------------------------------------
__global__ __launch_bounds__(256) void bucket_hist(const int* __restrict__ raw, int E,
                                                   int NF, int* __restrict__ bh,
                                                   const int* __restrict__ flag) {
    __shared__ int h[NF_PAD];
    int t = threadIdx.x;
    for (int i = t; i < NF_PAD; i += 256) h[i] = 0;
    __syncthreads();
    bool f64 = (*flag) != 0;
    long long base = (long long)blockIdx.x * PART_T;
    long long lim = base + PART_T;
    if (lim > (long long)E) lim = E;
    for (long long e = base + t; e < lim; e += 256) {
        int d = f64 ? raw[2 * ((long long)E + e)] : raw[E + e];
        atomicAdd(&h[d >> 6], 1);
    }
    __syncthreads();
    for (int i = t; i < NF; i += 256) {
        int v = h[i];
        if (v) atomicAdd(&bh[i], v);
    }
}

// ---------------------------------------------------------------------------
// Exclusive scan of bucket histogram -> boff, gcur; seeds noff[n]=E.
// ---------------------------------------------------------------------------
__global__ __launch_bounds__(1024) void bucket_scan(const int* __restrict__ bh,
                                                    int NF, int E, int n,
                                                    int* __restrict__ boff,
                                                    int* __restrict__ gcur,
                                                    int* __restrict__ noff) {
    __shared__ int h[NF_PAD];
    int t = threadIdx.x;
    h[t] = (t < NF) ? bh[t] : 0;
    __syncthreads();
    int v = h[t];
    for (int o = 1; o < 1024; o <<= 1) {
        int x = (t >= o) ? h[t - o] : 0;
        __syncthreads();
        h[t] += x;
        __syncthreads();
    }
    int exc = h[t] - v;
    if (t <= NF) boff[t] = (t == NF) ? E : exc;
    if (t < NF) gcur[t] = exc;
    if (t == 0) noff[n] = E;
}

// ---------------------------------------------------------------------------
// Partition edges into NF buckets by dst>>6, LDS-staged dense flushes.
// Payload: src | dst<<16 (requires N < 65536).
// ---------------------------------------------------------------------------
__global__ __launch_bounds__(256) void partition_edges(const int* __restrict__ raw, int E,
                                                       int NF, int* __restrict__ gcur,
                                                       unsigned* __restrict__ elist,
                                                       const int* __restrict__ flag) {
    __shared__ int cnt[NF_PAD];
    __shared__ int pfx[NF_PAD];
    __shared__ int gbase[NF_PAD];
    __shared__ int tsum[256];
    __shared__ unsigned stage[PART_T];
    int t = threadIdx.x;
    long long base = (long long)blockIdx.x * PART_T;
    int tileN = (int)min((long long)PART_T, (long long)E - base);
    bool f64 = (*flag) != 0;

    for (int i = t; i < NF_PAD; i += 256) cnt[i] = 0;
    __syncthreads();

    unsigned pk[PART_T / 256];
#pragma unroll
    for (int k = 0; k < PART_T / 256; k++) {
        long long e = base + k * 256 + t;
        if (e < (long long)E) {
            int s = f64 ? raw[2 * e] : raw[e];
            int d = f64 ? raw[2 * ((long long)E + e)] : raw[E + e];
            unsigned p = (unsigned)s | ((unsigned)d << 16);
            pk[k] = p;
            atomicAdd(&cnt[d >> 6], 1);
        } else {
            pk[k] = 0xFFFFFFFFu;
        }
    }
    __syncthreads();

    // block exclusive scan of cnt -> pfx
    int a0 = cnt[4 * t], a1 = cnt[4 * t + 1], a2 = cnt[4 * t + 2], a3 = cnt[4 * t + 3];
    int tot = a0 + a1 + a2 + a3;
    tsum[t] = tot;
    __syncthreads();
    for (int o = 1; o < 256; o <<= 1) {
        int x = (t >= o) ? tsum[t - o] : 0;
        __syncthreads();
        tsum[t] += x;
        __syncthreads();
    }
    int pre = tsum[t] - tot;
    pfx[4 * t] = pre;
    pfx[4 * t + 1] = pre + a0;
    pfx[4 * t + 2] = pre + a0 + a1;
    pfx[4 * t + 3] = pre + a0 + a1 + a2;

    for (int i = t; i < NF; i += 256) {
        gbase[i] = (cnt[i] > 0) ? atomicAdd(&gcur[i], cnt[i]) : 0;
    }
    __syncthreads();
    for (int i = t; i < NF_PAD; i += 256) cnt[i] = 0;
    __syncthreads();

#pragma unroll
    for (int k = 0; k < PART_T / 256; k++) {
        long long e = base + k * 256 + t;
        if (e < (long long)E) {
            unsigned p = pk[k];
            int f = p >> 22;
            int r = atomicAdd(&cnt[f], 1);
            stage[pfx[f] + r] = p;
        }
    }
    __syncthreads();

    for (int i = t; i < tileN; i += 256) {
        unsigned v = stage[i];
        int f = v >> 22;
        elist[gbase[f] + (i - pfx[f])] = v;
    }
}

// ---------------------------------------------------------------------------
// Exact CSR within each bucket: one block per bucket. First pass counts the
// 64 local degrees in LDS (window is L2-hot), prefix -> noff + dis + cursors,
// second pass ticket-scatters ushort src. Block owns its output window so
// writes stay dense in one XCD's L2.
// ---------------------------------------------------------------------------
__global__ __launch_bounds__(256) void bucket_csr(const unsigned* __restrict__ elist,
                                                  const int* __restrict__ boff,
                                                  int n,
                                                  unsigned short* __restrict__ ssrc,
                                                  int* __restrict__ noff,
                                                  float* __restrict__ dis) {
    __shared__ int cnt[64];
    __shared__ int cur[64];
    int b = blockIdx.x;
    int t = threadIdx.x;
    int beg = boff[b], end = boff[b + 1];
    if (t < 64) cnt[t] = 0;
    __syncthreads();
    for (int e = beg + t; e < end; e += 256) {
        unsigned v = elist[e];
        atomicAdd(&cnt[(v >> 16) & 63], 1);
    }
    __syncthreads();
    if (t < 64) {
        int d = cnt[t];
        int v = d;
#pragma unroll
        for (int o = 1; o < 64; o <<= 1) {
            int x = __shfl_up(v, o, 64);
            if (t >= o) v += x;
        }
        int exc = beg + v - d;  // exclusive prefix
        cur[t] = exc;
        int node = b * 64 + t;
        if (node <= n) noff[node] = exc;
        if (node < n) dis[node] = rsqrtf((float)(d + 1));  // +1 self-loop
    }
    __syncthreads();
    for (int e = beg + t; e < end; e += 256) {
        unsigned v = elist[e];
        int pos = atomicAdd(&cur[(v >> 16) & 63], 1);
        ssrc[pos] = (unsigned short)(v & 0xFFFFu);
    }
}

// ---------------------------------------------------------------------------
// out[n][64] = dis[n] * (in[n][64] @ W[64][64]).  W in 64 VGPRs/thread.
// ---------------------------------------------------------------------------
__global__ __launch_bounds__(256) void linear64(const float* __restrict__ in,
                                                const float* __restrict__ W,
                                                const float* __restrict__ dis,
                                                float* __restrict__ out, int n) {
    __shared__ float sIn[4][64];
    int t = threadIdx.x;
    int ln = t >> 6, od = t & 63;
    float w[64];
#pragma unroll
    for (int k = 0; k < 64; k++) w[k] = W[k * 64 + od];
    int base = blockIdx.x * 64;
    for (int pass = 0; pass < 16; pass++) {
        int node0 = base + pass * 4;
        __syncthreads();
        {
            int nd = node0 + ln;
            sIn[ln][od] = (nd < n) ? in[(long long)nd * 64 + od] : 0.f;
        }
        __syncthreads();
        int node = node0 + ln;
        if (node < n) {
            float acc = 0.f;
#pragma unroll
            for (int k = 0; k < 64; k++) acc += sIn[ln][k] * w[k];
            out[(long long)node * 64 + od] = acc * dis[node];
        }
    }
}

// ---------------------------------------------------------------------------
// Pull aggregation: wave per dst node, lane = dim, 8-deep unroll.
// out[d] = relu( dis[d]*(sum_{s in N(d)} hs[s] + hs[d]) + bias )
// ---------------------------------------------------------------------------
__global__ __launch_bounds__(256) void gather_agg(const float* __restrict__ hs,
                                                  const int* __restrict__ noff,
                                                  const unsigned short* __restrict__ ssrc,
                                                  const float* __restrict__ dis,
                                                  const float* __restrict__ bias,
                                                  float* __restrict__ out, int n) {
    int t = threadIdx.x;
    int lane = t & 63;
    int node = blockIdx.x * 4 + (t >> 6);
    if (node >= n) return;
    int beg = noff[node], end = noff[node + 1];
    float acc = 0.f;
    int e = beg;
    for (; e + 8 <= end; e += 8) {
        int s0 = ssrc[e], s1 = ssrc[e + 1], s2 = ssrc[e + 2], s3 = ssrc[e + 3];
        int s4 = ssrc[e + 4], s5 = ssrc[e + 5], s6 = ssrc[e + 6], s7 = ssrc[e + 7];
        float v0 = hs[(long long)s0 * 64 + lane];
        float v1 = hs[(long long)s1 * 64 + lane];
        float v2 = hs[(long long)s2 * 64 + lane];
        float v3 = hs[(long long)s3 * 64 + lane];
        float v4 = hs[(long long)s4 * 64 + lane];
        float v5 = hs[(long long)s5 * 64 + lane];
        float v6 = hs[(long long)s6 * 64 + lane];
        float v7 = hs[(long long)s7 * 64 + lane];
        acc += ((v0 + v1) + (v2 + v3)) + ((v4 + v5) + (v6 + v7));
    }
    for (; e < end; e++) {
        acc += hs[(long long)ssrc[e] * 64 + lane];
    }
    acc += hs[(long long)node * 64 + lane];  // self-loop
    float v = dis[node] * acc + bias[lane];
    out[(long long)node * 64 + lane] = v > 0.f ? v : 0.f;
}

// ---------------------------------------------------------------------------
// Mean-pool sum: batch sorted -> per-wave register accumulation.
// ---------------------------------------------------------------------------
__global__ __launch_bounds__(256) void pool_sum(const float* __restrict__ h,
                                                const int* __restrict__ batch,
                                                float* __restrict__ psum,
                                                int* __restrict__ pcnt, int n) {
    int t = threadIdx.x;
    int lane = t & 63;
    int base = (blockIdx.x * 4 + (t >> 6)) * 32;
    float acc = 0.f;
    int g = -1, cnt = 0;
    for (int i = 0; i < 32; i++) {
        int node = base + i;
        if (node >= n) break;
        int bg = batch[node];
        if (bg != g) {
            if (g >= 0) {
                atomicAdd(&psum[g * 64 + lane], acc);
                if (lane == 0) atomicAdd(&pcnt[g], cnt);
            }
            g = bg; acc = 0.f; cnt = 0;
        }
        acc += h[(long long)node * 64 + lane];
        cnt++;
    }
    if (g >= 0) {
        atomicAdd(&psum[g * 64 + lane], acc);
        if (lane == 0) atomicAdd(&pcnt[g], cnt);
    }
}

__global__ __launch_bounds__(640) void final_fc(const float* __restrict__ psum,
                                                const int* __restrict__ pcnt,
                                                const float* __restrict__ Wfc,
                                                const float* __restrict__ bfc,
                                                float* __restrict__ out) {
    __shared__ float sP[64 * 64];
    __shared__ float sW[64 * 10];
    int t = threadIdx.x;
    for (int i = t; i < 4096; i += 640) sP[i] = psum[i];
    if (t < 640) sW[t] = Wfc[t];
    __syncthreads();
    int g = t / 10, c = t % 10;
    float acc = 0.f;
#pragma unroll
    for (int k = 0; k < 64; k++) acc += sP[g * 64 + k] * sW[k * 10 + c];
    float cnt = (float)pcnt[g];
    if (cnt < 1.f) cnt = 1.f;
    out[g * 10 + c] = acc / cnt + bfc[c];
}

static inline int cdiv(long long a, int b) { return (int)((a + b - 1) / b); }

extern "C" void kernel_launch(void* const* d_in, const int* in_sizes, int n_in,
                              void* d_out, int out_size, void* d_ws, size_t ws_size,
                              hipStream_t stream) {
    const float* x    = (const float*)d_in[0];
    const int*   eraw = (const int*)d_in[1];
    const int*   braw = (const int*)d_in[2];
    const float* W1   = (const float*)d_in[3];
    const float* b1   = (const float*)d_in[4];
    const float* W2   = (const float*)d_in[5];
    const float* b2   = (const float*)d_in[6];
    const float* Wfc  = (const float*)d_in[7];
    const float* bfc  = (const float*)d_in[8];
    float* out = (float*)d_out;

    const int N  = in_sizes[0] / 64;   // 50000
    const int E  = in_sizes[1] / 2;    // 1600000
    const int NF = cdiv(N, 64);        // 782 buckets

    // ---- workspace carve (256B-aligned chunks) ----
    char* p = (char*)d_ws;
    auto carve = [&](size_t bytes) { char* q = p; p += (bytes + 255) / 256 * 256; return q; };
    int*            flag   = (int*)carve(4);
    unsigned*       elist  = (unsigned*)carve((size_t)E * sizeof(unsigned));
    unsigned short* ssrc   = (unsigned short*)carve((size_t)E * sizeof(unsigned short));
    int*            batchi = (int*)carve((size_t)N * sizeof(int));
    int*            bh     = (int*)carve((size_t)NF * sizeof(int));
    int*            boff   = (int*)carve((size_t)(NF + 1) * sizeof(int));
    int*            gcur   = (int*)carve((size_t)NF * sizeof(int));
    int*            noff   = (int*)carve((size_t)(NF * 64 + 1) * sizeof(int));
    float*          dis    = (float*)carve((size_t)N * sizeof(float));
    float*          bufA   = (float*)carve((size_t)N * 64 * sizeof(float));
    float*          bufB   = (float*)carve((size_t)N * 64 * sizeof(float));
    float*          psum   = (float*)carve(64 * 64 * sizeof(float));
    int*            pcnt   = (int*)carve(64 * sizeof(int));

    hipMemsetAsync(bh, 0, (size_t)NF * sizeof(int), stream);
    hipMemsetAsync(psum, 0, 64 * 64 * sizeof(float), stream);
    hipMemsetAsync(pcnt, 0, 64 * sizeof(int), stream);

    // ---- index dtype detect + batch convert ----
    detect_i64<<<1, THREADS, 0, stream>>>((const unsigned*)eraw, flag);
    convert_idx<<<cdiv(N, THREADS), THREADS, 0, stream>>>(braw, batchi, N, flag);

    // ---- bucket histogram + scan + dense partition + exact CSR (+dis) ----
    bucket_hist<<<cdiv(E, PART_T), 256, 0, stream>>>(eraw, E, NF, bh, flag);
    bucket_scan<<<1, 1024, 0, stream>>>(bh, NF, E, N, boff, gcur, noff);
    partition_edges<<<cdiv(E, PART_T), 256, 0, stream>>>(eraw, E, NF, gcur, elist, flag);
    bucket_csr<<<NF, 256, 0, stream>>>(elist, boff, N, ssrc, noff, dis);

    // ---- layer 1 ----
    linear64<<<cdiv(N, 64), 256, 0, stream>>>(x, W1, dis, bufA, N);
    gather_agg<<<cdiv(N, 4), 256, 0, stream>>>(bufA, noff, ssrc, dis, b1, bufB, N);

    // ---- layer 2 ----
    linear64<<<cdiv(N, 64), 256, 0, stream>>>(bufB, W2, dis, bufA, N);
    gather_agg<<<cdiv(N, 4), 256, 0, stream>>>(bufA, noff, ssrc, dis, b2, bufB, N);

    // ---- pool + head ----
    pool_sum<<<cdiv(N, 128), 256, 0, stream>>>(bufB, batchi, psum, pcnt, N);
    final_fc<<<1, 640, 0, stream>>>(psum, pcnt, Wfc, bfc, out);
}

// Round 6
// 309.020 us; speedup vs baseline: 5.4913x; 1.0206x over previous
//
#include <hip/hip_runtime.h>

#define THREADS 256
#define PART_T 8192      // edges per partition tile
#define NF_PAD 1024      // padded bucket count (NF = ceil(N/64) <= 1024)

// ---------------------------------------------------------------------------
// Detect whether the raw index array is int64 (high words all zero) or int32.
// ---------------------------------------------------------------------------
__global__ void detect_i64(const unsigned* __restrict__ raw, int* __restrict__ flag) {
    __shared__ int nz;
    if (threadIdx.x == 0) nz = 0;
    __syncthreads();
    int found = 0;
    for (int i = threadIdx.x; i < 2048; i += blockDim.x) {
        if (raw[2 * i + 1] != 0u) found = 1;
    }
    if (found) atomicOr(&nz, 1);
    __syncthreads();
    if (threadIdx.x == 0) *flag = nz ? 0 : 1;  // 1 => int64
}

__global__ void convert_idx(const int* __restrict__ raw, int* __restrict__ out,
                            int n, const int* __restrict__ flag) {
    int i = blockIdx.x * blockDim.x + threadIdx.x;
    if (i < n) out[i] = (*flag) ? raw[2 * i] : raw[i];
}

// ---------------------------------------------------------------------------
// Bucket-level histogram of dst>>6: LDS bins per block, one global flush.
// ---------------------------------------------------------------------------
__global__ __launch_bounds__(256) void bucket_hist(const int* __restrict__ raw, int E,
                                                   int NF, int* __restrict__ bh,
                                                   const int* __restrict__ flag) {
    __shared__ int h[NF_PAD];
    int t = threadIdx.x;
    for (int i = t; i < NF_PAD; i += 256) h[i] = 0;
    __syncthreads();
    bool f64 = (*flag) != 0;
    long long base = (long long)blockIdx.x * PART_T;
    long long lim = base + PART_T;
    if (lim > (long long)E) lim = E;
    for (long long e = base + t; e < lim; e += 256) {
        int d = f64 ? raw[2 * ((long long)E + e)] : raw[E + e];
        atomicAdd(&h[d >> 6], 1);
    }
    __syncthreads();
    for (int i = t; i < NF; i += 256) {
        int v = h[i];
        if (v) atomicAdd(&bh[i], v);
    }
}

// ---------------------------------------------------------------------------
// Exclusive scan of bucket histogram -> boff, gcur; seeds noff[n]=E.
// ---------------------------------------------------------------------------
__global__ __launch_bounds__(1024) void bucket_scan(const int* __restrict__ bh,
                                                    int NF, int E, int n,
                                                    int* __restrict__ boff,
                                                    int* __restrict__ gcur,
                                                    int* __restrict__ noff) {
    __shared__ int h[NF_PAD];
    int t = threadIdx.x;
    h[t] = (t < NF) ? bh[t] : 0;
    __syncthreads();
    int v = h[t];
    for (int o = 1; o < 1024; o <<= 1) {
        int x = (t >= o) ? h[t - o] : 0;
        __syncthreads();
        h[t] += x;
        __syncthreads();
    }
    int exc = h[t] - v;
    if (t <= NF) boff[t] = (t == NF) ? E : exc;
    if (t < NF) gcur[t] = exc;
    if (t == 0) noff[n] = E;
}

// ---------------------------------------------------------------------------
// Partition edges into NF buckets by dst>>6, LDS-staged dense flushes.
// Payload: src | dst<<16 (requires N < 65536).
// ---------------------------------------------------------------------------
__global__ __launch_bounds__(256) void partition_edges(const int* __restrict__ raw, int E,
                                                       int NF, int* __restrict__ gcur,
                                                       unsigned* __restrict__ elist,
                                                       const int* __restrict__ flag) {
    __shared__ int cnt[NF_PAD];
    __shared__ int pfx[NF_PAD];
    __shared__ int gbase[NF_PAD];
    __shared__ int tsum[256];
    __shared__ unsigned stage[PART_T];
    int t = threadIdx.x;
    long long base = (long long)blockIdx.x * PART_T;
    int tileN = (int)min((long long)PART_T, (long long)E - base);
    bool f64 = (*flag) != 0;

    for (int i = t; i < NF_PAD; i += 256) cnt[i] = 0;
    __syncthreads();

    unsigned pk[PART_T / 256];
#pragma unroll
    for (int k = 0; k < PART_T / 256; k++) {
        long long e = base + k * 256 + t;
        if (e < (long long)E) {
            int s = f64 ? raw[2 * e] : raw[e];
            int d = f64 ? raw[2 * ((long long)E + e)] : raw[E + e];
            unsigned p = (unsigned)s | ((unsigned)d << 16);
            pk[k] = p;
            atomicAdd(&cnt[d >> 6], 1);
        } else {
            pk[k] = 0xFFFFFFFFu;
        }
    }
    __syncthreads();

    // block exclusive scan of cnt -> pfx
    int a0 = cnt[4 * t], a1 = cnt[4 * t + 1], a2 = cnt[4 * t + 2], a3 = cnt[4 * t + 3];
    int tot = a0 + a1 + a2 + a3;
    tsum[t] = tot;
    __syncthreads();
    for (int o = 1; o < 256; o <<= 1) {
        int x = (t >= o) ? tsum[t - o] : 0;
        __syncthreads();
        tsum[t] += x;
        __syncthreads();
    }
    int pre = tsum[t] - tot;
    pfx[4 * t] = pre;
    pfx[4 * t + 1] = pre + a0;
    pfx[4 * t + 2] = pre + a0 + a1;
    pfx[4 * t + 3] = pre + a0 + a1 + a2;

    for (int i = t; i < NF; i += 256) {
        gbase[i] = (cnt[i] > 0) ? atomicAdd(&gcur[i], cnt[i]) : 0;
    }
    __syncthreads();
    for (int i = t; i < NF_PAD; i += 256) cnt[i] = 0;
    __syncthreads();

#pragma unroll
    for (int k = 0; k < PART_T / 256; k++) {
        long long e = base + k * 256 + t;
        if (e < (long long)E) {
            unsigned p = pk[k];
            int f = p >> 22;
            int r = atomicAdd(&cnt[f], 1);
            stage[pfx[f] + r] = p;
        }
    }
    __syncthreads();

    for (int i = t; i < tileN; i += 256) {
        unsigned v = stage[i];
        int f = v >> 22;
        elist[gbase[f] + (i - pfx[f])] = v;
    }
}

// ---------------------------------------------------------------------------
// Exact CSR within each bucket: one block per bucket; also emits dis[].
// ---------------------------------------------------------------------------
__global__ __launch_bounds__(256) void bucket_csr(const unsigned* __restrict__ elist,
                                                  const int* __restrict__ boff,
                                                  int n,
                                                  unsigned short* __restrict__ ssrc,
                                                  int* __restrict__ noff,
                                                  float* __restrict__ dis) {
    __shared__ int cnt[64];
    __shared__ int cur[64];
    int b = blockIdx.x;
    int t = threadIdx.x;
    int beg = boff[b], end = boff[b + 1];
    if (t < 64) cnt[t] = 0;
    __syncthreads();
    for (int e = beg + t; e < end; e += 256) {
        unsigned v = elist[e];
        atomicAdd(&cnt[(v >> 16) & 63], 1);
    }
    __syncthreads();
    if (t < 64) {
        int d = cnt[t];
        int v = d;
#pragma unroll
        for (int o = 1; o < 64; o <<= 1) {
            int x = __shfl_up(v, o, 64);
            if (t >= o) v += x;
        }
        int exc = beg + v - d;  // exclusive prefix
        cur[t] = exc;
        int node = b * 64 + t;
        if (node <= n) noff[node] = exc;
        if (node < n) dis[node] = rsqrtf((float)(d + 1));  // +1 self-loop
    }
    __syncthreads();
    for (int e = beg + t; e < end; e += 256) {
        unsigned v = elist[e];
        int pos = atomicAdd(&cur[(v >> 16) & 63], 1);
        ssrc[pos] = (unsigned short)(v & 0xFFFFu);
    }
}

// ---------------------------------------------------------------------------
// out[n][64] = dis[n] * (in[n][64] @ W[64][64]).  W in 64 VGPRs/thread.
// ---------------------------------------------------------------------------
__global__ __launch_bounds__(256) void linear64(const float* __restrict__ in,
                                                const float* __restrict__ W,
                                                const float* __restrict__ dis,
                                                float* __restrict__ out, int n) {
    __shared__ float sIn[4][64];
    int t = threadIdx.x;
    int ln = t >> 6, od = t & 63;
    float w[64];
#pragma unroll
    for (int k = 0; k < 64; k++) w[k] = W[k * 64 + od];
    int base = blockIdx.x * 64;
    for (int pass = 0; pass < 16; pass++) {
        int node0 = base + pass * 4;
        __syncthreads();
        {
            int nd = node0 + ln;
            sIn[ln][od] = (nd < n) ? in[(long long)nd * 64 + od] : 0.f;
        }
        __syncthreads();
        int node = node0 + ln;
        if (node < n) {
            float acc = 0.f;
#pragma unroll
            for (int k = 0; k < 64; k++) acc += sIn[ln][k] * w[k];
            out[(long long)node * 64 + od] = acc * dis[node];
        }
    }
}

// ---------------------------------------------------------------------------
// Pull aggregation, 4 edges per VMEM instruction.
// Wave = 1 dst node. Lane split: g = lane>>4 (edge slot 0..3), l = lane&15
// (float4 slot). Per 64-edge chunk: 1 lane-parallel ssrc load, indices
// distributed via __shfl; each iteration gathers 4 full 256B rows in ONE
// global_load_dwordx4. Epilogue: shfl_xor reduce over groups, float4 store.
// out[d] = relu( dis[d]*(sum hs[s] + hs[d]) + bias )
// ---------------------------------------------------------------------------
__global__ __launch_bounds__(256) void gather_agg(const float* __restrict__ hs,
                                                  const int* __restrict__ noff,
                                                  const unsigned short* __restrict__ ssrc,
                                                  const float* __restrict__ dis,
                                                  const float* __restrict__ bias,
                                                  float* __restrict__ out, int n) {
    int t = threadIdx.x;
    int lane = t & 63;
    int g = lane >> 4;      // edge slot within iteration
    int l = lane & 15;      // float4 slot within row
    int node = blockIdx.x * 4 + (t >> 6);
    if (node >= n) return;
    int beg = noff[node], end = noff[node + 1];
    float4 acc = make_float4(0.f, 0.f, 0.f, 0.f);

    for (int c = beg; c < end; c += 64) {
        int cnt = min(64, end - c);
        int myidx = (lane < cnt) ? (int)ssrc[c + lane] : 0;
#pragma unroll 4
        for (int j = 0; j < cnt; j += 4) {
            int s = __shfl(myidx, j + g, 64);
            float4 v = ((const float4*)(hs + (long long)s * 64))[l];
            if (j + g < cnt) {
                acc.x += v.x; acc.y += v.y; acc.z += v.z; acc.w += v.w;
            }
        }
    }
    // self-loop row added once (group 0 only)
    if (g == 0) {
        float4 v = ((const float4*)(hs + (long long)node * 64))[l];
        acc.x += v.x; acc.y += v.y; acc.z += v.z; acc.w += v.w;
    }
    // reduce across the 4 groups (lanes xor 16, 32)
#pragma unroll
    for (int o = 16; o <= 32; o <<= 1) {
        acc.x += __shfl_xor(acc.x, o, 64);
        acc.y += __shfl_xor(acc.y, o, 64);
        acc.z += __shfl_xor(acc.z, o, 64);
        acc.w += __shfl_xor(acc.w, o, 64);
    }
    if (g == 0) {
        float dv = dis[node];
        float4 bv = ((const float4*)bias)[l];
        float4 r;
        r.x = dv * acc.x + bv.x; r.x = r.x > 0.f ? r.x : 0.f;
        r.y = dv * acc.y + bv.y; r.y = r.y > 0.f ? r.y : 0.f;
        r.z = dv * acc.z + bv.z; r.z = r.z > 0.f ? r.z : 0.f;
        r.w = dv * acc.w + bv.w; r.w = r.w > 0.f ? r.w : 0.f;
        ((float4*)(out + (long long)node * 64))[l] = r;
    }
}

// ---------------------------------------------------------------------------
// Mean-pool sum: batch sorted -> per-wave register accumulation.
// ---------------------------------------------------------------------------
__global__ __launch_bounds__(256) void pool_sum(const float* __restrict__ h,
                                                const int* __restrict__ batch,
                                                float* __restrict__ psum,
                                                int* __restrict__ pcnt, int n) {
    int t = threadIdx.x;
    int lane = t & 63;
    int base = (blockIdx.x * 4 + (t >> 6)) * 32;
    float acc = 0.f;
    int g = -1, cnt = 0;
    for (int i = 0; i < 32; i++) {
        int node = base + i;
        if (node >= n) break;
        int bg = batch[node];
        if (bg != g) {
            if (g >= 0) {
                atomicAdd(&psum[g * 64 + lane], acc);
                if (lane == 0) atomicAdd(&pcnt[g], cnt);
            }
            g = bg; acc = 0.f; cnt = 0;
        }
        acc += h[(long long)node * 64 + lane];
        cnt++;
    }
    if (g >= 0) {
        atomicAdd(&psum[g * 64 + lane], acc);
        if (lane == 0) atomicAdd(&pcnt[g], cnt);
    }
}

__global__ __launch_bounds__(640) void final_fc(const float* __restrict__ psum,
                                                const int* __restrict__ pcnt,
                                                const float* __restrict__ Wfc,
                                                const float* __restrict__ bfc,
                                                float* __restrict__ out) {
    __shared__ float sP[64 * 64];
    __shared__ float sW[64 * 10];
    int t = threadIdx.x;
    for (int i = t; i < 4096; i += 640) sP[i] = psum[i];
    if (t < 640) sW[t] = Wfc[t];
    __syncthreads();
    int g = t / 10, c = t % 10;
    float acc = 0.f;
#pragma unroll
    for (int k = 0; k < 64; k++) acc += sP[g * 64 + k] * sW[k * 10 + c];
    float cnt = (float)pcnt[g];
    if (cnt < 1.f) cnt = 1.f;
    out[g * 10 + c] = acc / cnt + bfc[c];
}

static inline int cdiv(long long a, int b) { return (int)((a + b - 1) / b); }

extern "C" void kernel_launch(void* const* d_in, const int* in_sizes, int n_in,
                              void* d_out, int out_size, void* d_ws, size_t ws_size,
                              hipStream_t stream) {
    const float* x    = (const float*)d_in[0];
    const int*   eraw = (const int*)d_in[1];
    const int*   braw = (const int*)d_in[2];
    const float* W1   = (const float*)d_in[3];
    const float* b1   = (const float*)d_in[4];
    const float* W2   = (const float*)d_in[5];
    const float* b2   = (const float*)d_in[6];
    const float* Wfc  = (const float*)d_in[7];
    const float* bfc  = (const float*)d_in[8];
    float* out = (float*)d_out;

    const int N  = in_sizes[0] / 64;   // 50000
    const int E  = in_sizes[1] / 2;    // 1600000
    const int NF = cdiv(N, 64);        // 782 buckets

    // ---- workspace carve (256B-aligned chunks) ----
    char* p = (char*)d_ws;
    auto carve = [&](size_t bytes) { char* q = p; p += (bytes + 255) / 256 * 256; return q; };
    int*            flag   = (int*)carve(4);
    unsigned*       elist  = (unsigned*)carve((size_t)E * sizeof(unsigned));
    unsigned short* ssrc   = (unsigned short*)carve((size_t)E * sizeof(unsigned short));
    int*            batchi = (int*)carve((size_t)N * sizeof(int));
    int*            bh     = (int*)carve((size_t)NF * sizeof(int));
    int*            boff   = (int*)carve((size_t)(NF + 1) * sizeof(int));
    int*            gcur   = (int*)carve((size_t)NF * sizeof(int));
    int*            noff   = (int*)carve((size_t)(NF * 64 + 1) * sizeof(int));
    float*          dis    = (float*)carve((size_t)N * sizeof(float));
    float*          bufA   = (float*)carve((size_t)N * 64 * sizeof(float));
    float*          bufB   = (float*)carve((size_t)N * 64 * sizeof(float));
    float*          psum   = (float*)carve(64 * 64 * sizeof(float));
    int*            pcnt   = (int*)carve(64 * sizeof(int));

    hipMemsetAsync(bh, 0, (size_t)NF * sizeof(int), stream);
    hipMemsetAsync(psum, 0, 64 * 64 * sizeof(float), stream);
    hipMemsetAsync(pcnt, 0, 64 * sizeof(int), stream);

    // ---- index dtype detect + batch convert ----
    detect_i64<<<1, THREADS, 0, stream>>>((const unsigned*)eraw, flag);
    convert_idx<<<cdiv(N, THREADS), THREADS, 0, stream>>>(braw, batchi, N, flag);

    // ---- bucket histogram + scan + dense partition + exact CSR (+dis) ----
    bucket_hist<<<cdiv(E, PART_T), 256, 0, stream>>>(eraw, E, NF, bh, flag);
    bucket_scan<<<1, 1024, 0, stream>>>(bh, NF, E, N, boff, gcur, noff);
    partition_edges<<<cdiv(E, PART_T), 256, 0, stream>>>(eraw, E, NF, gcur, elist, flag);
    bucket_csr<<<NF, 256, 0, stream>>>(elist, boff, N, ssrc, noff, dis);

    // ---- layer 1 ----
    linear64<<<cdiv(N, 64), 256, 0, stream>>>(x, W1, dis, bufA, N);
    gather_agg<<<cdiv(N, 4), 256, 0, stream>>>(bufA, noff, ssrc, dis, b1, bufB, N);

    // ---- layer 2 ----
    linear64<<<cdiv(N, 64), 256, 0, stream>>>(bufB, W2, dis, bufA, N);
    gather_agg<<<cdiv(N, 4), 256, 0, stream>>>(bufA, noff, ssrc, dis, b2, bufB, N);

    // ---- pool + head ----
    pool_sum<<<cdiv(N, 128), 256, 0, stream>>>(bufB, batchi, psum, pcnt, N);
    final_fc<<<1, 640, 0, stream>>>(psum, pcnt, Wfc, bfc, out);
}

// Round 7
// 271.867 us; speedup vs baseline: 6.2417x; 1.1367x over previous
//
#include <hip/hip_runtime.h>
#include <hip/hip_bf16.h>

#define THREADS 256
#define PART_T 8192      // edges per partition tile
#define NF_PAD 1024      // padded bucket count (NF = ceil(N/64) <= 1024)

// ---------------------------------------------------------------------------
// Detect whether the raw index array is int64 (high words all zero) or int32.
// ---------------------------------------------------------------------------
__global__ void detect_i64(const unsigned* __restrict__ raw, int* __restrict__ flag) {
    __shared__ int nz;
    if (threadIdx.x == 0) nz = 0;
    __syncthreads();
    int found = 0;
    for (int i = threadIdx.x; i < 2048; i += blockDim.x) {
        if (raw[2 * i + 1] != 0u) found = 1;
    }
    if (found) atomicOr(&nz, 1);
    __syncthreads();
    if (threadIdx.x == 0) *flag = nz ? 0 : 1;  // 1 => int64
}

__global__ void convert_idx(const int* __restrict__ raw, int* __restrict__ out,
                            int n, const int* __restrict__ flag) {
    int i = blockIdx.x * blockDim.x + threadIdx.x;
    if (i < n) out[i] = (*flag) ? raw[2 * i] : raw[i];
}

// ---------------------------------------------------------------------------
// Bucket-level histogram of dst>>6: LDS bins per block, one global flush.
// ---------------------------------------------------------------------------
__global__ __launch_bounds__(256) void bucket_hist(const int* __restrict__ raw, int E,
                                                   int NF, int* __restrict__ bh,
                                                   const int* __restrict__ flag) {
    __shared__ int h[NF_PAD];
    int t = threadIdx.x;
    for (int i = t; i < NF_PAD; i += 256) h[i] = 0;
    __syncthreads();
    bool f64 = (*flag) != 0;
    long long base = (long long)blockIdx.x * PART_T;
    long long lim = base + PART_T;
    if (lim > (long long)E) lim = E;
    for (long long e = base + t; e < lim; e += 256) {
        int d = f64 ? raw[2 * ((long long)E + e)] : raw[E + e];
        atomicAdd(&h[d >> 6], 1);
    }
    __syncthreads();
    for (int i = t; i < NF; i += 256) {
        int v = h[i];
        if (v) atomicAdd(&bh[i], v);
    }
}

// ---------------------------------------------------------------------------
// Exclusive scan of bucket histogram -> boff, gcur; seeds noff[n]=E.
// ---------------------------------------------------------------------------
__global__ __launch_bounds__(1024) void bucket_scan(const int* __restrict__ bh,
                                                    int NF, int E, int n,
                                                    int* __restrict__ boff,
                                                    int* __restrict__ gcur,
                                                    int* __restrict__ noff) {
    __shared__ int h[NF_PAD];
    int t = threadIdx.x;
    h[t] = (t < NF) ? bh[t] : 0;
    __syncthreads();
    int v = h[t];
    for (int o = 1; o < 1024; o <<= 1) {
        int x = (t >= o) ? h[t - o] : 0;
        __syncthreads();
        h[t] += x;
        __syncthreads();
    }
    int exc = h[t] - v;
    if (t <= NF) boff[t] = (t == NF) ? E : exc;
    if (t < NF) gcur[t] = exc;
    if (t == 0) noff[n] = E;
}

// ---------------------------------------------------------------------------
// Partition edges into NF buckets by dst>>6, LDS-staged dense flushes.
// Payload: src | dst<<16 (requires N < 65536).
// ---------------------------------------------------------------------------
__global__ __launch_bounds__(256) void partition_edges(const int* __restrict__ raw, int E,
                                                       int NF, int* __restrict__ gcur,
                                                       unsigned* __restrict__ elist,
                                                       const int* __restrict__ flag) {
    __shared__ int cnt[NF_PAD];
    __shared__ int pfx[NF_PAD];
    __shared__ int gbase[NF_PAD];
    __shared__ int tsum[256];
    __shared__ unsigned stage[PART_T];
    int t = threadIdx.x;
    long long base = (long long)blockIdx.x * PART_T;
    int tileN = (int)min((long long)PART_T, (long long)E - base);
    bool f64 = (*flag) != 0;

    for (int i = t; i < NF_PAD; i += 256) cnt[i] = 0;
    __syncthreads();

    unsigned pk[PART_T / 256];
#pragma unroll
    for (int k = 0; k < PART_T / 256; k++) {
        long long e = base + k * 256 + t;
        if (e < (long long)E) {
            int s = f64 ? raw[2 * e] : raw[e];
            int d = f64 ? raw[2 * ((long long)E + e)] : raw[E + e];
            unsigned p = (unsigned)s | ((unsigned)d << 16);
            pk[k] = p;
            atomicAdd(&cnt[d >> 6], 1);
        } else {
            pk[k] = 0xFFFFFFFFu;
        }
    }
    __syncthreads();

    // block exclusive scan of cnt -> pfx
    int a0 = cnt[4 * t], a1 = cnt[4 * t + 1], a2 = cnt[4 * t + 2], a3 = cnt[4 * t + 3];
    int tot = a0 + a1 + a2 + a3;
    tsum[t] = tot;
    __syncthreads();
    for (int o = 1; o < 256; o <<= 1) {
        int x = (t >= o) ? tsum[t - o] : 0;
        __syncthreads();
        tsum[t] += x;
        __syncthreads();
    }
    int pre = tsum[t] - tot;
    pfx[4 * t] = pre;
    pfx[4 * t + 1] = pre + a0;
    pfx[4 * t + 2] = pre + a0 + a1;
    pfx[4 * t + 3] = pre + a0 + a1 + a2;

    for (int i = t; i < NF; i += 256) {
        gbase[i] = (cnt[i] > 0) ? atomicAdd(&gcur[i], cnt[i]) : 0;
    }
    __syncthreads();
    for (int i = t; i < NF_PAD; i += 256) cnt[i] = 0;
    __syncthreads();

#pragma unroll
    for (int k = 0; k < PART_T / 256; k++) {
        long long e = base + k * 256 + t;
        if (e < (long long)E) {
            unsigned p = pk[k];
            int f = p >> 22;
            int r = atomicAdd(&cnt[f], 1);
            stage[pfx[f] + r] = p;
        }
    }
    __syncthreads();

    for (int i = t; i < tileN; i += 256) {
        unsigned v = stage[i];
        int f = v >> 22;
        elist[gbase[f] + (i - pfx[f])] = v;
    }
}

// ---------------------------------------------------------------------------
// Exact CSR within each bucket: one block per bucket; also emits dis[].
// ---------------------------------------------------------------------------
__global__ __launch_bounds__(256) void bucket_csr(const unsigned* __restrict__ elist,
                                                  const int* __restrict__ boff,
                                                  int n,
                                                  unsigned short* __restrict__ ssrc,
                                                  int* __restrict__ noff,
                                                  float* __restrict__ dis) {
    __shared__ int cnt[64];
    __shared__ int cur[64];
    int b = blockIdx.x;
    int t = threadIdx.x;
    int beg = boff[b], end = boff[b + 1];
    if (t < 64) cnt[t] = 0;
    __syncthreads();
    for (int e = beg + t; e < end; e += 256) {
        unsigned v = elist[e];
        atomicAdd(&cnt[(v >> 16) & 63], 1);
    }
    __syncthreads();
    if (t < 64) {
        int d = cnt[t];
        int v = d;
#pragma unroll
        for (int o = 1; o < 64; o <<= 1) {
            int x = __shfl_up(v, o, 64);
            if (t >= o) v += x;
        }
        int exc = beg + v - d;  // exclusive prefix
        cur[t] = exc;
        int node = b * 64 + t;
        if (node <= n) noff[node] = exc;
        if (node < n) dis[node] = rsqrtf((float)(d + 1));  // +1 self-loop
    }
    __syncthreads();
    for (int e = beg + t; e < end; e += 256) {
        unsigned v = elist[e];
        int pos = atomicAdd(&cur[(v >> 16) & 63], 1);
        ssrc[pos] = (unsigned short)(v & 0xFFFFu);
    }
}

// ---------------------------------------------------------------------------
// outH[n][64] = bf16( dis[n] * (in[n][64] @ W[64][64]) ).  W in 64 VGPRs.
// ---------------------------------------------------------------------------
__global__ __launch_bounds__(256) void linear64(const float* __restrict__ in,
                                                const float* __restrict__ W,
                                                const float* __restrict__ dis,
                                                __hip_bfloat16* __restrict__ outH, int n) {
    __shared__ float sIn[4][64];
    int t = threadIdx.x;
    int ln = t >> 6, od = t & 63;
    float w[64];
#pragma unroll
    for (int k = 0; k < 64; k++) w[k] = W[k * 64 + od];
    int base = blockIdx.x * 64;
    for (int pass = 0; pass < 16; pass++) {
        int node0 = base + pass * 4;
        __syncthreads();
        {
            int nd = node0 + ln;
            sIn[ln][od] = (nd < n) ? in[(long long)nd * 64 + od] : 0.f;
        }
        __syncthreads();
        int node = node0 + ln;
        if (node < n) {
            float acc = 0.f;
#pragma unroll
            for (int k = 0; k < 64; k++) acc += sIn[ln][k] * w[k];
            outH[(long long)node * 64 + od] = __float2bfloat16(acc * dis[node]);
        }
    }
}

__device__ __forceinline__ float bf_lo(unsigned u) { return __uint_as_float(u << 16); }
__device__ __forceinline__ float bf_hi(unsigned u) { return __uint_as_float(u & 0xFFFF0000u); }

// ---------------------------------------------------------------------------
// Pull aggregation over bf16 hs rows (128 B each), 8 edges per VMEM inst.
// Wave = 1 dst node. g = lane>>3 (edge slot 0..7), l = lane&7 (16B slice).
// fp32 accumulate; shfl_xor reduce over the 8 groups; fp32 output.
// out[d] = relu( dis[d]*(sum hs[s] + hs[d]) + bias )
// ---------------------------------------------------------------------------
__global__ __launch_bounds__(256) void gather_agg(const unsigned short* __restrict__ hs,
                                                  const int* __restrict__ noff,
                                                  const unsigned short* __restrict__ ssrc,
                                                  const float* __restrict__ dis,
                                                  const float* __restrict__ bias,
                                                  float* __restrict__ out, int n) {
    int t = threadIdx.x;
    int lane = t & 63;
    int g = lane >> 3;      // edge slot within iteration (0..7)
    int l = lane & 7;       // 16B slice within row (0..7)
    int node = blockIdx.x * 4 + (t >> 6);
    if (node >= n) return;
    int beg = noff[node], end = noff[node + 1];
    float a0 = 0.f, a1 = 0.f, a2 = 0.f, a3 = 0.f, a4 = 0.f, a5 = 0.f, a6 = 0.f, a7 = 0.f;

    for (int c = beg; c < end; c += 64) {
        int cnt = min(64, end - c);
        int myidx = (lane < cnt) ? (int)ssrc[c + lane] : 0;
#pragma unroll 2
        for (int j = 0; j < cnt; j += 8) {
            int s = __shfl(myidx, j + g, 64);
            uint4 v = ((const uint4*)(hs + (long long)s * 64))[l];
            if (j + g < cnt) {
                a0 += bf_lo(v.x); a1 += bf_hi(v.x);
                a2 += bf_lo(v.y); a3 += bf_hi(v.y);
                a4 += bf_lo(v.z); a5 += bf_hi(v.z);
                a6 += bf_lo(v.w); a7 += bf_hi(v.w);
            }
        }
    }
    // self-loop row added once (group 0 only)
    if (g == 0) {
        uint4 v = ((const uint4*)(hs + (long long)node * 64))[l];
        a0 += bf_lo(v.x); a1 += bf_hi(v.x);
        a2 += bf_lo(v.y); a3 += bf_hi(v.y);
        a4 += bf_lo(v.z); a5 += bf_hi(v.z);
        a6 += bf_lo(v.w); a7 += bf_hi(v.w);
    }
    // reduce across the 8 groups (lanes xor 8, 16, 32)
#pragma unroll
    for (int o = 8; o <= 32; o <<= 1) {
        a0 += __shfl_xor(a0, o, 64);
        a1 += __shfl_xor(a1, o, 64);
        a2 += __shfl_xor(a2, o, 64);
        a3 += __shfl_xor(a3, o, 64);
        a4 += __shfl_xor(a4, o, 64);
        a5 += __shfl_xor(a5, o, 64);
        a6 += __shfl_xor(a6, o, 64);
        a7 += __shfl_xor(a7, o, 64);
    }
    if (g == 0) {
        float dv = dis[node];
        const float4* bp = (const float4*)bias;
        float4 b0 = bp[2 * l], b1 = bp[2 * l + 1];
        float4 r0, r1;
        r0.x = dv * a0 + b0.x; r0.x = r0.x > 0.f ? r0.x : 0.f;
        r0.y = dv * a1 + b0.y; r0.y = r0.y > 0.f ? r0.y : 0.f;
        r0.z = dv * a2 + b0.z; r0.z = r0.z > 0.f ? r0.z : 0.f;
        r0.w = dv * a3 + b0.w; r0.w = r0.w > 0.f ? r0.w : 0.f;
        r1.x = dv * a4 + b1.x; r1.x = r1.x > 0.f ? r1.x : 0.f;
        r1.y = dv * a5 + b1.y; r1.y = r1.y > 0.f ? r1.y : 0.f;
        r1.z = dv * a6 + b1.z; r1.z = r1.z > 0.f ? r1.z : 0.f;
        r1.w = dv * a7 + b1.w; r1.w = r1.w > 0.f ? r1.w : 0.f;
        float4* op = (float4*)(out + (long long)node * 64);
        op[2 * l] = r0;
        op[2 * l + 1] = r1;
    }
}

// ---------------------------------------------------------------------------
// Mean-pool sum: batch sorted -> per-wave register accumulation.
// ---------------------------------------------------------------------------
__global__ __launch_bounds__(256) void pool_sum(const float* __restrict__ h,
                                                const int* __restrict__ batch,
                                                float* __restrict__ psum,
                                                int* __restrict__ pcnt, int n) {
    int t = threadIdx.x;
    int lane = t & 63;
    int base = (blockIdx.x * 4 + (t >> 6)) * 32;
    float acc = 0.f;
    int g = -1, cnt = 0;
    for (int i = 0; i < 32; i++) {
        int node = base + i;
        if (node >= n) break;
        int bg = batch[node];
        if (bg != g) {
            if (g >= 0) {
                atomicAdd(&psum[g * 64 + lane], acc);
                if (lane == 0) atomicAdd(&pcnt[g], cnt);
            }
            g = bg; acc = 0.f; cnt = 0;
        }
        acc += h[(long long)node * 64 + lane];
        cnt++;
    }
    if (g >= 0) {
        atomicAdd(&psum[g * 64 + lane], acc);
        if (lane == 0) atomicAdd(&pcnt[g], cnt);
    }
}

__global__ __launch_bounds__(640) void final_fc(const float* __restrict__ psum,
                                                const int* __restrict__ pcnt,
                                                const float* __restrict__ Wfc,
                                                const float* __restrict__ bfc,
                                                float* __restrict__ out) {
    __shared__ float sP[64 * 64];
    __shared__ float sW[64 * 10];
    int t = threadIdx.x;
    for (int i = t; i < 4096; i += 640) sP[i] = psum[i];
    if (t < 640) sW[t] = Wfc[t];
    __syncthreads();
    int g = t / 10, c = t % 10;
    float acc = 0.f;
#pragma unroll
    for (int k = 0; k < 64; k++) acc += sP[g * 64 + k] * sW[k * 10 + c];
    float cnt = (float)pcnt[g];
    if (cnt < 1.f) cnt = 1.f;
    out[g * 10 + c] = acc / cnt + bfc[c];
}

static inline int cdiv(long long a, int b) { return (int)((a + b - 1) / b); }

extern "C" void kernel_launch(void* const* d_in, const int* in_sizes, int n_in,
                              void* d_out, int out_size, void* d_ws, size_t ws_size,
                              hipStream_t stream) {
    const float* x    = (const float*)d_in[0];
    const int*   eraw = (const int*)d_in[1];
    const int*   braw = (const int*)d_in[2];
    const float* W1   = (const float*)d_in[3];
    const float* b1   = (const float*)d_in[4];
    const float* W2   = (const float*)d_in[5];
    const float* b2   = (const float*)d_in[6];
    const float* Wfc  = (const float*)d_in[7];
    const float* bfc  = (const float*)d_in[8];
    float* out = (float*)d_out;

    const int N  = in_sizes[0] / 64;   // 50000
    const int E  = in_sizes[1] / 2;    // 1600000
    const int NF = cdiv(N, 64);        // 782 buckets

    // ---- workspace carve (256B-aligned chunks) ----
    char* p = (char*)d_ws;
    auto carve = [&](size_t bytes) { char* q = p; p += (bytes + 255) / 256 * 256; return q; };
    int*            flag   = (int*)carve(4);
    unsigned*       elist  = (unsigned*)carve((size_t)E * sizeof(unsigned));
    unsigned short* ssrc   = (unsigned short*)carve((size_t)E * sizeof(unsigned short));
    int*            batchi = (int*)carve((size_t)N * sizeof(int));
    int*            bh     = (int*)carve((size_t)NF * sizeof(int));
    int*            boff   = (int*)carve((size_t)(NF + 1) * sizeof(int));
    int*            gcur   = (int*)carve((size_t)NF * sizeof(int));
    int*            noff   = (int*)carve((size_t)(NF * 64 + 1) * sizeof(int));
    float*          dis    = (float*)carve((size_t)N * sizeof(float));
    __hip_bfloat16* bufH   = (__hip_bfloat16*)carve((size_t)N * 64 * sizeof(__hip_bfloat16));
    float*          bufA   = (float*)carve((size_t)N * 64 * sizeof(float));
    float*          bufB   = (float*)carve((size_t)N * 64 * sizeof(float));
    float*          psum   = (float*)carve(64 * 64 * sizeof(float));
    int*            pcnt   = (int*)carve(64 * sizeof(int));

    hipMemsetAsync(bh, 0, (size_t)NF * sizeof(int), stream);
    hipMemsetAsync(psum, 0, 64 * 64 * sizeof(float), stream);
    hipMemsetAsync(pcnt, 0, 64 * sizeof(int), stream);

    // ---- index dtype detect + batch convert ----
    detect_i64<<<1, THREADS, 0, stream>>>((const unsigned*)eraw, flag);
    convert_idx<<<cdiv(N, THREADS), THREADS, 0, stream>>>(braw, batchi, N, flag);

    // ---- bucket histogram + scan + dense partition + exact CSR (+dis) ----
    bucket_hist<<<cdiv(E, PART_T), 256, 0, stream>>>(eraw, E, NF, bh, flag);
    bucket_scan<<<1, 1024, 0, stream>>>(bh, NF, E, N, boff, gcur, noff);
    partition_edges<<<cdiv(E, PART_T), 256, 0, stream>>>(eraw, E, NF, gcur, elist, flag);
    bucket_csr<<<NF, 256, 0, stream>>>(elist, boff, N, ssrc, noff, dis);

    // ---- layer 1 ----
    linear64<<<cdiv(N, 64), 256, 0, stream>>>(x, W1, dis, bufH, N);
    gather_agg<<<cdiv(N, 4), 256, 0, stream>>>((const unsigned short*)bufH, noff, ssrc, dis, b1, bufA, N);

    // ---- layer 2 ----
    linear64<<<cdiv(N, 64), 256, 0, stream>>>(bufA, W2, dis, bufH, N);
    gather_agg<<<cdiv(N, 4), 256, 0, stream>>>((const unsigned short*)bufH, noff, ssrc, dis, b2, bufB, N);

    // ---- pool + head ----
    pool_sum<<<cdiv(N, 128), 256, 0, stream>>>(bufB, batchi, psum, pcnt, N);
    final_fc<<<1, 640, 0, stream>>>(psum, pcnt, Wfc, bfc, out);
}